// Round 2
// baseline (3981.919 us; speedup 1.0000x reference)
//
#include <hip/hip_runtime.h>
#include <hip/hip_bf16.h>

typedef __hip_bfloat16 bf16;
typedef __attribute__((ext_vector_type(4))) float f32x4;
typedef __attribute__((ext_vector_type(8))) short s16x8;

__device__ __forceinline__ float sigf(float x) {
    return 1.0f / (1.0f + __expf(-x));
}
__device__ __forceinline__ float tanh_f(float x) {
    float ax = fabsf(x);
    float e = __expf(-2.0f * ax);
    float r = (1.0f - e) / (1.0f + e);
    return x < 0.0f ? -r : r;
}

// ---------------------------------------------------------------------------
// embW[d][v][n] = sum_e emb[v][e]*W1[e][orig(n)] + b1[orig(n)], n = u*4+g
// ---------------------------------------------------------------------------
__global__ void k_embw(const float* __restrict__ emb,
                       const float* __restrict__ W1f, const float* __restrict__ b1f,
                       const float* __restrict__ W1b, const float* __restrict__ b1b,
                       float* __restrict__ embW) {
    int c = blockIdx.x * 256 + threadIdx.x;   // original column 0..2047
    int v = blockIdx.y;                        // 0..29
    int d = blockIdx.z;                        // 0..1
    const float* W = d ? W1b : W1f;
    const float* b = d ? b1b : b1f;
    float acc = b[c];
    const float* er = emb + v * 128;
#pragma unroll 8
    for (int e = 0; e < 128; ++e) acc += er[e] * W[e * 2048 + c];
    int n = ((c & 511) << 2) | (c >> 9);
    embW[(d * 30 + v) * 2048 + n] = acc;
}

// b2r[d][n] = b2[d][orig(n)]
__global__ void k_b2r(const float* __restrict__ b2f, const float* __restrict__ b2b,
                      float* __restrict__ dst) {
    int i = blockIdx.x * 256 + threadIdx.x;  // 0..4095
    int d = i >> 11, n = i & 2047;
    int c = ((n & 3) << 9) | (n >> 2);
    dst[i] = (d ? b2b : b2f)[c];
}

// ---------------------------------------------------------------------------
// Tiled transpose(+gate reorder) f32 [K][ncols] -> bf16 [ncols][kpitch] at koff
// 64x64 tile = 4096 elements = 256 threads x 16 iterations.
// ---------------------------------------------------------------------------
template<int REORDER>
__global__ void k_trans(const float* __restrict__ src, bf16* __restrict__ dst,
                        int ncols, int kpitch, int koff) {
    __shared__ float tile[64][65];
    int k0 = blockIdx.x * 64;
    int c0 = blockIdx.y * 64;
    int tid = threadIdx.x;
#pragma unroll
    for (int i = 0; i < 16; ++i) {
        int seg = tid + i * 256;
        int r = seg >> 6, cc = seg & 63;
        tile[r][cc] = src[(size_t)(k0 + r) * ncols + c0 + cc];
    }
    __syncthreads();
#pragma unroll
    for (int i = 0; i < 16; ++i) {
        int seg = tid + i * 256;
        int nl = seg >> 6, kl = seg & 63;
        int c = c0 + nl;
        int n = REORDER ? (((c & 511) << 2) | (c >> 9)) : c;
        dst[(size_t)n * kpitch + koff + k0 + kl] = __float2bfloat16(tile[kl][nl]);
    }
}

// ---------------------------------------------------------------------------
// The workhorse: 128x128-tile MFMA GEMM + fused epilogue.
// MODE 0: layer-1 LSTM step  (K=512,  A=h_in,            add=embW gather, gates)
// MODE 1: layer-2 LSTM step  (K=1536, A=[h1seq[t]|h_in], add=bias,        gates)
// MODE 2: dense              (K=1024, A=[hf|hb],         add=bd, relu -> dbuf)
// ---------------------------------------------------------------------------
template<int MODE>
__global__ __launch_bounds__(256, 2)
void k_step(const bf16* __restrict__ A1, const bf16* __restrict__ A2,
            const bf16* __restrict__ Bt, const float* __restrict__ table,
            const int* __restrict__ xin, float* __restrict__ c_st,
            bf16* __restrict__ h_out, bf16* __restrict__ h1s, int t)
{
    constexpr int NCH = (MODE == 0) ? 16 : (MODE == 1) ? 48 : 32;   // K/32 chunks
    constexpr int BP  = (MODE == 0) ? 512 : (MODE == 1) ? 1536 : 1024;

    __shared__ __align__(16) short ldss[20480];   // 40 KB: staging, reused for z
    short* const AS0 = ldss;
    short* const BS0 = ldss + 5120;
    short* const AS1 = ldss + 10240;
    short* const BS1 = ldss + 15360;

    const int tid  = threadIdx.x;
    const int lane = tid & 63;
    const int wv   = tid >> 6;
    const int wm   = (wv >> 1) << 6;
    const int wn   = (wv & 1) << 6;
    const int n0   = blockIdx.x << 7;
    const int m0   = blockIdx.y << 7;

    const int dir = (MODE == 2) ? 0 : (m0 >= 1024);
    const int t_a = dir ? 63 - t : t;

    const bf16* a1base;
    if constexpr (MODE == 1)
        a1base = A1 + ((size_t)t_a << 20) + ((size_t)(m0 & 1023) << 10);
    else
        a1base = A1 + (size_t)m0 * 512;
    const bf16* const btbase = Bt + (size_t)dir * 2048 * BP + (size_t)n0 * BP;

    const int sr0 = tid >> 2;           // staging row 0..63 (and +64)
    const int sc0 = (tid & 3) << 3;     // staging col element 0/8/16/24

    auto ald = [&](int kc, int r) -> float4 {
        const int k = (kc << 5) + sc0;
        const bf16* p;
        if constexpr (MODE == 0)
            p = a1base + (size_t)r * 512 + k;
        else if constexpr (MODE == 1)
            p = (kc < 32) ? a1base + (size_t)r * 1024 + k
                          : A2 + (size_t)(m0 + r) * 512 + (k - 1024);
        else
            p = (kc < 16) ? a1base + (size_t)r * 512 + k
                          : A2 + (size_t)(m0 + r) * 512 + (k - 512);
        return *(const float4*)p;
    };
    auto bld = [&](int kc, int r) -> float4 {
        return *(const float4*)(btbase + (size_t)r * BP + (kc << 5) + sc0);
    };

    f32x4 acc[4][4];
#pragma unroll
    for (int i = 0; i < 4; ++i)
#pragma unroll
        for (int j = 0; j < 4; ++j) acc[i][j] = (f32x4){0.f, 0.f, 0.f, 0.f};

    {   // prologue stage chunk 0
        float4 a0 = ald(0, sr0), a1 = ald(0, sr0 + 64);
        float4 b0 = bld(0, sr0), b1 = bld(0, sr0 + 64);
        *(float4*)&AS0[sr0 * 40 + sc0] = a0;
        *(float4*)&AS0[(sr0 + 64) * 40 + sc0] = a1;
        *(float4*)&BS0[sr0 * 40 + sc0] = b0;
        *(float4*)&BS0[(sr0 + 64) * 40 + sc0] = b1;
    }

    const int rl = lane & 15;
    const int q8 = (lane >> 4) << 3;

    for (int kc = 0; kc < NCH; ++kc) {
        __syncthreads();
        const int buf = kc & 1;
        const short* as = buf ? AS1 : AS0;
        const short* bs = buf ? BS1 : BS0;
        float4 a0, a1, b0, b1;
        const bool pf = (kc + 1 < NCH);
        if (pf) {   // issue next-chunk loads before compute (latency hiding)
            a0 = ald(kc + 1, sr0); a1 = ald(kc + 1, sr0 + 64);
            b0 = bld(kc + 1, sr0); b1 = bld(kc + 1, sr0 + 64);
        }
        s16x8 af[4], bfq[4];
#pragma unroll
        for (int f = 0; f < 4; ++f)
            af[f] = *(const s16x8*)&as[(wm + f * 16 + rl) * 40 + q8];
#pragma unroll
        for (int f = 0; f < 4; ++f)
            bfq[f] = *(const s16x8*)&bs[(wn + f * 16 + rl) * 40 + q8];
#pragma unroll
        for (int fm = 0; fm < 4; ++fm)
#pragma unroll
            for (int fn = 0; fn < 4; ++fn)
                acc[fm][fn] = __builtin_amdgcn_mfma_f32_16x16x32_bf16(
                    af[fm], bfq[fn], acc[fm][fn], 0, 0, 0);
        if (pf) {
            short* asn = buf ? AS0 : AS1;
            short* bsn = buf ? BS0 : BS1;
            *(float4*)&asn[sr0 * 40 + sc0] = a0;
            *(float4*)&asn[(sr0 + 64) * 40 + sc0] = a1;
            *(float4*)&bsn[sr0 * 40 + sc0] = b0;
            *(float4*)&bsn[(sr0 + 64) * 40 + sc0] = b1;
        }
    }

    if constexpr (MODE == 2) {
        // dense: bias + relu, direct stores to dbuf[1024][1024]
#pragma unroll
        for (int fn = 0; fn < 4; ++fn) {
            const int col = n0 + wn + fn * 16 + rl;
            const float bdv = table[col];
#pragma unroll
            for (int fm = 0; fm < 4; ++fm) {
                const int rb = m0 + wm + fm * 16 + ((lane >> 4) << 2);
#pragma unroll
                for (int r = 0; r < 4; ++r) {
                    float v = acc[fm][fn][r] + bdv;
                    h_out[(size_t)(rb + r) * 1024 + col] =
                        __float2bfloat16(v > 0.f ? v : 0.f);
                }
            }
        }
    } else {
        // gates epilogue: two 64-row halves through z LDS (overlays staging)
        float* z = (float*)ldss;   // [64][132] f32
        const int u0 = n0 >> 2;
        for (int half = 0; half < 2; ++half) {
            __syncthreads();
            if ((wv >> 1) == half) {
#pragma unroll
                for (int fm = 0; fm < 4; ++fm)
#pragma unroll
                    for (int fn = 0; fn < 4; ++fn) {
                        const int zr = fm * 16 + ((lane >> 4) << 2);
                        const int zc = wn + fn * 16 + rl;
#pragma unroll
                        for (int r = 0; r < 4; ++r)
                            z[(zr + r) * 132 + zc] = acc[fm][fn][r];
                    }
            }
            __syncthreads();
#pragma unroll 2
            for (int j = 0; j < 8; ++j) {
                const int cid = j * 256 + tid;
                const int ml = cid >> 5;
                const int ul = cid & 31;
                const int mg = m0 + half * 64 + ml;
                const int b  = mg & 1023;
                float4 z4 = *(float4*)&z[ml * 132 + (ul << 2)];
                const float* tab;
                if constexpr (MODE == 0) {
                    const int v = xin[(b << 6) + t_a];
                    tab = table + (size_t)(dir * 30 + v) * 2048;
                } else {
                    tab = table + dir * 2048;
                }
                const float4 tv = *(const float4*)&tab[n0 + (ul << 2)];
                const float zi = z4.x + tv.x, zf = z4.y + tv.y;
                const float zg = z4.z + tv.z, zo = z4.w + tv.w;
                const float ig = sigf(zi), fg = sigf(zf);
                const float gg = tanh_f(zg), og = sigf(zo);
                const size_t cu = (size_t)mg * 512 + u0 + ul;
                const float cn = fg * c_st[cu] + ig * gg;
                c_st[cu] = cn;
                const float h = og * tanh_f(cn);
                h_out[cu] = __float2bfloat16(h);
                if constexpr (MODE == 0)
                    h1s[(((size_t)t_a << 10) + b) * 1024 + (dir << 9) + u0 + ul] =
                        __float2bfloat16(h);
            }
        }
    }
}

// ---------------------------------------------------------------------------
// out[b][o] = dbuf[b] . Wo[:,o] + bo[o]   (block per row, wave per 5 outputs)
// ---------------------------------------------------------------------------
__global__ __launch_bounds__(256)
void k_out(const bf16* __restrict__ dbuf, const float* __restrict__ Wo,
           const float* __restrict__ bo, float* __restrict__ out) {
    int b = blockIdx.x, tid = threadIdx.x;
    int wv = tid >> 6, lane = tid & 63;
    float acc[5] = {0.f, 0.f, 0.f, 0.f, 0.f};
    for (int kk = 0; kk < 1024; kk += 64) {
        float a = __bfloat162float(dbuf[b * 1024 + kk + lane]);
#pragma unroll
        for (int j = 0; j < 5; ++j)
            acc[j] += a * Wo[(kk + lane) * 20 + wv + j * 4];
    }
#pragma unroll
    for (int j = 0; j < 5; ++j) {
        float s = acc[j];
        for (int off = 32; off; off >>= 1) s += __shfl_down(s, off, 64);
        if (lane == 0) out[b * 20 + wv + j * 4] = s + bo[wv + j * 4];
    }
}

// ---------------------------------------------------------------------------
extern "C" void kernel_launch(void* const* d_in, const int* in_sizes, int n_in,
                              void* d_out, int out_size, void* d_ws, size_t ws_size,
                              hipStream_t stream) {
    const int*   x   = (const int*)  d_in[0];
    const float* emb = (const float*)d_in[1];
    const float* W1f = (const float*)d_in[2];
    const float* U1f = (const float*)d_in[3];
    const float* b1f = (const float*)d_in[4];
    const float* W1b = (const float*)d_in[5];
    const float* U1b = (const float*)d_in[6];
    const float* b1b = (const float*)d_in[7];
    const float* W2f = (const float*)d_in[8];
    const float* U2f = (const float*)d_in[9];
    const float* b2f = (const float*)d_in[10];
    const float* W2b = (const float*)d_in[11];
    const float* U2b = (const float*)d_in[12];
    const float* b2b = (const float*)d_in[13];
    const float* Wd  = (const float*)d_in[14];
    const float* bd  = (const float*)d_in[15];
    const float* Wo  = (const float*)d_in[16];
    const float* bo  = (const float*)d_in[17];

    char* ws = (char*)d_ws;
    float* embW = (float*)(ws + 0);               // [2][30][2048] f32
    float* b2r  = (float*)(ws + 491520);          // [2][2048] f32
    bf16* Ut1   = (bf16*)(ws + 507904);           // [2][2048][512]
    bf16* BigBt = (bf16*)(ws + 4702208);          // [2][2048][1536]
    bf16* Wdt   = (bf16*)(ws + 17285120);         // [1024][1024]
    bf16* hA    = (bf16*)(ws + 19382272);         // [2048][512]
    bf16* hB    = (bf16*)(ws + 21479424);         // [2048][512]
    float* cst  = (float*)(ws + 23576576);        // [2048][512] f32
    bf16* dbuf  = (bf16*)(ws + 27770880);         // [1024][1024]
    bf16* h1seq = (bf16*)(ws + 29868032);         // [64][1024][1024]
    // total ws use: 164,085,760 bytes

    // ---- prep: tables + weight transposes (gate-interleaved col order) ----
    k_embw<<<dim3(8, 30, 2), 256, 0, stream>>>(emb, W1f, b1f, W1b, b1b, embW);
    k_b2r<<<16, 256, 0, stream>>>(b2f, b2b, b2r);
    k_trans<1><<<dim3(8, 32), 256, 0, stream>>>(U1f, Ut1,              2048, 512, 0);
    k_trans<1><<<dim3(8, 32), 256, 0, stream>>>(U1b, Ut1 + 2048 * 512, 2048, 512, 0);
    k_trans<1><<<dim3(16, 32), 256, 0, stream>>>(W2f, BigBt,                2048, 1536, 0);
    k_trans<1><<<dim3(8, 32), 256, 0, stream>>>(U2f, BigBt,                2048, 1536, 1024);
    k_trans<1><<<dim3(16, 32), 256, 0, stream>>>(W2b, BigBt + 2048 * 1536, 2048, 1536, 0);
    k_trans<1><<<dim3(8, 32), 256, 0, stream>>>(U2b, BigBt + 2048 * 1536, 2048, 1536, 1024);
    k_trans<0><<<dim3(16, 16), 256, 0, stream>>>(Wd, Wdt, 1024, 1024, 0);

    // ---- layer 1 (fwd+bwd stacked as M=2048) ----
    hipMemsetAsync(hA, 0, (size_t)2048 * 512 * sizeof(bf16), stream);
    hipMemsetAsync(cst, 0, (size_t)2048 * 512 * sizeof(float), stream);
    bf16 *hin = hA, *hout = hB;
    for (int t = 0; t < 64; ++t) {
        k_step<0><<<dim3(16, 16), 256, 0, stream>>>(
            hin, (const bf16*)nullptr, Ut1, embW, x, cst, hout, h1seq, t);
        bf16* tmp = hin; hin = hout; hout = tmp;
    }

    // ---- layer 2 (K = 1024 (h1 via W2) + 512 (recurrent U2)) ----
    hipMemsetAsync(hin, 0, (size_t)2048 * 512 * sizeof(bf16), stream);
    hipMemsetAsync(cst, 0, (size_t)2048 * 512 * sizeof(float), stream);
    for (int t = 0; t < 64; ++t) {
        k_step<1><<<dim3(16, 16), 256, 0, stream>>>(
            h1seq, hin, BigBt, b2r, (const int*)nullptr, cst, hout,
            (bf16*)nullptr, t);
        bf16* tmp = hin; hin = hout; hout = tmp;
    }
    // hin now holds the final layer-2 hidden state [2048][512]

    // ---- dense + relu, then output projection ----
    k_step<2><<<dim3(8, 8), 256, 0, stream>>>(
        hin, hin + (size_t)1024 * 512, Wdt, bd, (const int*)nullptr,
        (float*)nullptr, dbuf, (bf16*)nullptr, 0);
    k_out<<<1024, 256, 0, stream>>>(dbuf, Wo, bo, (float*)d_out);
}

// Round 3
// 2602.656 us; speedup vs baseline: 1.5299x; 1.5299x over previous
//
#include <hip/hip_runtime.h>
#include <hip/hip_bf16.h>

typedef __hip_bfloat16 bf16;
typedef __attribute__((ext_vector_type(4))) float f32x4;
typedef __attribute__((ext_vector_type(8))) short s16x8;

__device__ __forceinline__ float sigf(float x) {
    return 1.0f / (1.0f + __expf(-x));
}
__device__ __forceinline__ float tanh_f(float x) {
    float ax = fabsf(x);
    float e = __expf(-2.0f * ax);
    float r = (1.0f - e) / (1.0f + e);
    return x < 0.0f ? -r : r;
}

#define GLL16(src, ldst)                                                      \
    __builtin_amdgcn_global_load_lds(                                         \
        (const __attribute__((address_space(1))) void*)(src),                 \
        (__attribute__((address_space(3))) void*)(ldst), 16, 0, 0)

// ---------------------------------------------------------------------------
// embW[d][v][n] = sum_e emb[v][e]*W1[e][orig(n)] + b1[orig(n)], n = u*4+g
// (epilogue table, f32, NOT a GEMM operand -> no XOR swizzle)
// ---------------------------------------------------------------------------
__global__ void k_embw(const float* __restrict__ emb,
                       const float* __restrict__ W1f, const float* __restrict__ b1f,
                       const float* __restrict__ W1b, const float* __restrict__ b1b,
                       float* __restrict__ embW) {
    int c = blockIdx.x * 256 + threadIdx.x;   // original column 0..2047
    int v = blockIdx.y;                        // 0..29
    int d = blockIdx.z;                        // 0..1
    const float* W = d ? W1b : W1f;
    const float* b = d ? b1b : b1f;
    float acc = b[c];
    const float* er = emb + v * 128;
#pragma unroll 8
    for (int e = 0; e < 128; ++e) acc += er[e] * W[e * 2048 + c];
    int n = ((c & 511) << 2) | (c >> 9);
    embW[(d * 30 + v) * 2048 + n] = acc;
}

// b2r[d][n] = b2[d][orig(n)]
__global__ void k_b2r(const float* __restrict__ b2f, const float* __restrict__ b2b,
                      float* __restrict__ dst) {
    int i = blockIdx.x * 256 + threadIdx.x;  // 0..4095
    int d = i >> 11, n = i & 2047;
    int c = ((n & 3) << 9) | (n >> 2);
    dst[i] = (d ? b2b : b2f)[c];
}

// ---------------------------------------------------------------------------
// Tiled transpose(+gate reorder) f32 [K][ncols] -> bf16 [ncols][kpitch] at koff
// Output rows carry the LDS XOR swizzle: element k stored at k ^ ((n&7)<<3)
// (XOR touches bits 3..5 of k only -> stays within its 64-element chunk).
// ---------------------------------------------------------------------------
template<int REORDER>
__global__ void k_trans(const float* __restrict__ src, bf16* __restrict__ dst,
                        int ncols, int kpitch, int koff) {
    __shared__ float tile[64][65];
    int k0 = blockIdx.x * 64;
    int c0 = blockIdx.y * 64;
    int tid = threadIdx.x;
#pragma unroll
    for (int i = 0; i < 16; ++i) {
        int seg = tid + i * 256;
        int r = seg >> 6, cc = seg & 63;
        tile[r][cc] = src[(size_t)(k0 + r) * ncols + c0 + cc];
    }
    __syncthreads();
#pragma unroll
    for (int i = 0; i < 16; ++i) {
        int seg = tid + i * 256;
        int nl = seg >> 6, kl = seg & 63;
        int c = c0 + nl;
        int n = REORDER ? (((c & 511) << 2) | (c >> 9)) : c;
        int kabs = koff + k0 + kl;
        dst[(size_t)n * kpitch + (kabs ^ ((n & 7) << 3))] =
            __float2bfloat16(tile[kl][nl]);
    }
}

// ---------------------------------------------------------------------------
// 128x128-tile MFMA GEMM + fused epilogue; global_load_lds staging from
// pre-swizzled operands, 64-K double-buffered chunks, XCD-aware block map.
// MODE 0: layer-1 LSTM step  (K=512,  A=h_in,            add=embW gather)
// MODE 1: layer-2 LSTM step  (K=1536, A=[h1seq[t]|h_in], add=bias)
// MODE 2: dense              (K=1024, A=[hf|hb],         add=bd, relu)
// ---------------------------------------------------------------------------
template<int MODE>
__global__ __launch_bounds__(256, 2)
void k_step(const bf16* __restrict__ A1, const bf16* __restrict__ A2,
            const bf16* __restrict__ Bt, const float* __restrict__ table,
            const int* __restrict__ xin, float* __restrict__ c_st,
            bf16* __restrict__ h_out, bf16* __restrict__ h1s, int t)
{
    constexpr int NCH = (MODE == 0) ? 8 : (MODE == 1) ? 24 : 16;  // 64-K chunks
    constexpr int BP  = (MODE == 0) ? 512 : (MODE == 1) ? 1536 : 1024;

    // 64 KB: two buffers x (A[128][64] + B[128][64]) bf16; epilogue z overlays
    __shared__ __align__(16) short ldss[32768];

    const int tid  = threadIdx.x;
    const int lane = tid & 63;
    const int wv   = tid >> 6;
    const int wm   = (wv >> 1) << 6;
    const int wn   = (wv & 1) << 6;

    int n0, m0;
    if constexpr (MODE == 2) {
        n0 = (blockIdx.x & 7) << 7;
        m0 = (blockIdx.x >> 3) << 7;
    } else {
        // XCD swizzle: xcd = bid&7 owns n-panel pair -> B stays in per-XCD L2
        const int xcd = blockIdx.x & 7, y = blockIdx.x >> 3;
        n0 = (((xcd << 1) | (y >> 4))) << 7;
        m0 = (y & 15) << 7;
    }

    const int dir = (MODE == 2) ? 0 : (m0 >= 1024);
    const int t_a = dir ? 63 - t : t;

    const char* a1b;
    if constexpr (MODE == 1)
        a1b = (const char*)(A1 + ((size_t)t_a << 20) + ((size_t)(m0 & 1023) << 10));
    else
        a1b = (const char*)(A1 + (size_t)m0 * 512);
    const char* const btb = (const char*)(Bt + (size_t)dir * 2048 * BP + (size_t)n0 * BP);
    const char* const a2b = (const char*)A2;

    // stage chunk c (64 k-elements of A and B panels) into LDS buffer `half`
    auto stage = [&](int c, int half) {
        char* base = (char*)ldss + half * 32768;
#pragma unroll
        for (int i = 0; i < 4; ++i) {
            const int u = i * 256 + tid;
            const int r = u >> 3, j = u & 7;     // row 0..127, 16B-unit 0..7
            const char* src;
            if constexpr (MODE == 0)
                src = a1b + r * 1024 + c * 128 + j * 16;
            else if constexpr (MODE == 1)
                src = (c < 16) ? a1b + r * 2048 + c * 128 + j * 16
                               : a2b + (size_t)(m0 + r) * 1024 + (c - 16) * 128 + j * 16;
            else
                src = (c < 8) ? a1b + r * 1024 + c * 128 + j * 16
                              : a2b + (size_t)(m0 + r) * 1024 + (c - 8) * 128 + j * 16;
            GLL16(src, base + (i * 256 + wv * 64) * 16);
        }
#pragma unroll
        for (int i = 0; i < 4; ++i) {
            const int u = i * 256 + tid;
            const int r = u >> 3, j = u & 7;
            const char* src = btb + (size_t)r * (BP * 2) + c * 128 + j * 16;
            GLL16(src, base + 16384 + (i * 256 + wv * 64) * 16);
        }
    };

    f32x4 acc[4][4];
#pragma unroll
    for (int i = 0; i < 4; ++i)
#pragma unroll
        for (int j = 0; j < 4; ++j) acc[i][j] = (f32x4){0.f, 0.f, 0.f, 0.f};

    stage(0, 0);

    const int rl = lane & 15;
    const int q8 = (lane >> 4) << 3;
    const int xk = (rl & 7) << 3;            // XOR key (elements)

    for (int c = 0; c < NCH; ++c) {
        __syncthreads();                      // drains vmcnt+lgkm: buf[c&1] ready
        if (c + 1 < NCH) stage(c + 1, (c + 1) & 1);
        const short* as = ldss + (c & 1) * 16384;
        const short* bs = as + 8192;
#pragma unroll
        for (int ks = 0; ks < 2; ++ks) {
            const int eo = ((ks << 5) + q8) ^ xk;
            s16x8 af[4], bq[4];
#pragma unroll
            for (int f = 0; f < 4; ++f)
                af[f] = *(const s16x8*)&as[(wm + f * 16 + rl) * 64 + eo];
#pragma unroll
            for (int f = 0; f < 4; ++f)
                bq[f] = *(const s16x8*)&bs[(wn + f * 16 + rl) * 64 + eo];
#pragma unroll
            for (int fm = 0; fm < 4; ++fm)
#pragma unroll
                for (int fn = 0; fn < 4; ++fn)
                    acc[fm][fn] = __builtin_amdgcn_mfma_f32_16x16x32_bf16(
                        af[fm], bq[fn], acc[fm][fn], 0, 0, 0);
        }
    }

    if constexpr (MODE == 2) {
        // dense: bias + relu, direct stores to dbuf[1024][1024] (unswizzled)
#pragma unroll
        for (int fn = 0; fn < 4; ++fn) {
            const int col = n0 + wn + fn * 16 + rl;
            const float bdv = table[col];
#pragma unroll
            for (int fm = 0; fm < 4; ++fm) {
                const int rb = m0 + wm + fm * 16 + ((lane >> 4) << 2);
#pragma unroll
                for (int r = 0; r < 4; ++r) {
                    float v = acc[fm][fn][r] + bdv;
                    h_out[(size_t)(rb + r) * 1024 + col] =
                        __float2bfloat16(v > 0.f ? v : 0.f);
                }
            }
        }
    } else {
        // gates epilogue: two 64-row halves through z LDS (overlays staging)
        float* z = (float*)ldss;   // [64][132] f32 = 33792 B < 65536 B
        const int u0 = n0 >> 2;
        for (int half = 0; half < 2; ++half) {
            __syncthreads();
            if ((wv >> 1) == half) {
#pragma unroll
                for (int fm = 0; fm < 4; ++fm)
#pragma unroll
                    for (int fn = 0; fn < 4; ++fn) {
                        const int zr = fm * 16 + ((lane >> 4) << 2);
                        const int zc = wn + fn * 16 + rl;
#pragma unroll
                        for (int r = 0; r < 4; ++r)
                            z[(zr + r) * 132 + zc] = acc[fm][fn][r];
                    }
            }
            __syncthreads();
#pragma unroll 2
            for (int j = 0; j < 8; ++j) {
                const int cid = j * 256 + tid;
                const int ml = cid >> 5;
                const int ul = cid & 31;
                const int mg = m0 + half * 64 + ml;
                const int b  = mg & 1023;
                float4 z4 = *(float4*)&z[ml * 132 + (ul << 2)];
                const float* tab;
                if constexpr (MODE == 0) {
                    const int v = xin[(b << 6) + t_a];
                    tab = table + (size_t)(dir * 30 + v) * 2048;
                } else {
                    tab = table + dir * 2048;
                }
                const float4 tv = *(const float4*)&tab[n0 + (ul << 2)];
                const float zi = z4.x + tv.x, zf = z4.y + tv.y;
                const float zg = z4.z + tv.z, zo = z4.w + tv.w;
                const float ig = sigf(zi), fg = sigf(zf);
                const float gg = tanh_f(zg), og = sigf(zo);
                const size_t cu = (size_t)mg * 512 + u0 + ul;   // c_st unswizzled
                const float cn = fg * c_st[cu] + ig * gg;
                c_st[cu] = cn;
                const float h = og * tanh_f(cn);
                // h stored pre-swizzled for next step's linear global_load_lds
                const int us = (u0 + ul) ^ ((mg & 7) << 3);
                h_out[(size_t)mg * 512 + us] = __float2bfloat16(h);
                if constexpr (MODE == 0) {
                    const int col = (((dir << 9) | (u0 + ul)) ^ ((b & 7) << 3));
                    h1s[(((size_t)t_a << 10) + b) * 1024 + col] =
                        __float2bfloat16(h);
                }
            }
        }
    }
}

// ---------------------------------------------------------------------------
// out[b][o] = dbuf[b] . Wo[:,o] + bo[o]   (block per row, wave per 5 outputs)
// ---------------------------------------------------------------------------
__global__ __launch_bounds__(256)
void k_out(const bf16* __restrict__ dbuf, const float* __restrict__ Wo,
           const float* __restrict__ bo, float* __restrict__ out) {
    int b = blockIdx.x, tid = threadIdx.x;
    int wv = tid >> 6, lane = tid & 63;
    float acc[5] = {0.f, 0.f, 0.f, 0.f, 0.f};
    for (int kk = 0; kk < 1024; kk += 64) {
        float a = __bfloat162float(dbuf[b * 1024 + kk + lane]);
#pragma unroll
        for (int j = 0; j < 5; ++j)
            acc[j] += a * Wo[(kk + lane) * 20 + wv + j * 4];
    }
#pragma unroll
    for (int j = 0; j < 5; ++j) {
        float s = acc[j];
        for (int off = 32; off; off >>= 1) s += __shfl_down(s, off, 64);
        if (lane == 0) out[b * 20 + wv + j * 4] = s + bo[wv + j * 4];
    }
}

// ---------------------------------------------------------------------------
extern "C" void kernel_launch(void* const* d_in, const int* in_sizes, int n_in,
                              void* d_out, int out_size, void* d_ws, size_t ws_size,
                              hipStream_t stream) {
    const int*   x   = (const int*)  d_in[0];
    const float* emb = (const float*)d_in[1];
    const float* W1f = (const float*)d_in[2];
    const float* U1f = (const float*)d_in[3];
    const float* b1f = (const float*)d_in[4];
    const float* W1b = (const float*)d_in[5];
    const float* U1b = (const float*)d_in[6];
    const float* b1b = (const float*)d_in[7];
    const float* W2f = (const float*)d_in[8];
    const float* U2f = (const float*)d_in[9];
    const float* b2f = (const float*)d_in[10];
    const float* W2b = (const float*)d_in[11];
    const float* U2b = (const float*)d_in[12];
    const float* b2b = (const float*)d_in[13];
    const float* Wd  = (const float*)d_in[14];
    const float* bd  = (const float*)d_in[15];
    const float* Wo  = (const float*)d_in[16];
    const float* bo  = (const float*)d_in[17];

    char* ws = (char*)d_ws;
    float* embW = (float*)(ws + 0);               // [2][30][2048] f32
    float* b2r  = (float*)(ws + 491520);          // [2][2048] f32
    bf16* Ut1   = (bf16*)(ws + 507904);           // [2][2048][512]  (swizzled)
    bf16* BigBt = (bf16*)(ws + 4702208);          // [2][2048][1536] (swizzled)
    bf16* Wdt   = (bf16*)(ws + 17285120);         // [1024][1024]    (swizzled)
    bf16* hA    = (bf16*)(ws + 19382272);         // [2048][512]     (swizzled)
    bf16* hB    = (bf16*)(ws + 21479424);         // [2048][512]     (swizzled)
    float* cst  = (float*)(ws + 23576576);        // [2048][512] f32
    bf16* dbuf  = (bf16*)(ws + 27770880);         // [1024][1024]
    bf16* h1seq = (bf16*)(ws + 29868032);         // [64][1024][1024] (swizzled)
    // total ws use: 164,085,760 bytes

    // ---- prep: tables + weight transposes (gate-interleave + XOR swizzle) ----
    k_embw<<<dim3(8, 30, 2), 256, 0, stream>>>(emb, W1f, b1f, W1b, b1b, embW);
    k_b2r<<<16, 256, 0, stream>>>(b2f, b2b, b2r);
    k_trans<1><<<dim3(8, 32), 256, 0, stream>>>(U1f, Ut1,              2048, 512, 0);
    k_trans<1><<<dim3(8, 32), 256, 0, stream>>>(U1b, Ut1 + 2048 * 512, 2048, 512, 0);
    k_trans<1><<<dim3(16, 32), 256, 0, stream>>>(W2f, BigBt,                2048, 1536, 0);
    k_trans<1><<<dim3(8, 32), 256, 0, stream>>>(U2f, BigBt,                2048, 1536, 1024);
    k_trans<1><<<dim3(16, 32), 256, 0, stream>>>(W2b, BigBt + 2048 * 1536, 2048, 1536, 0);
    k_trans<1><<<dim3(8, 32), 256, 0, stream>>>(U2b, BigBt + 2048 * 1536, 2048, 1536, 1024);
    k_trans<0><<<dim3(16, 16), 256, 0, stream>>>(Wd, Wdt, 1024, 1024, 0);

    // ---- layer 1 (fwd+bwd stacked as M=2048) ----
    hipMemsetAsync(hA, 0, (size_t)2048 * 512 * sizeof(bf16), stream);
    hipMemsetAsync(cst, 0, (size_t)2048 * 512 * sizeof(float), stream);
    bf16 *hin = hA, *hout = hB;
    for (int t = 0; t < 64; ++t) {
        k_step<0><<<256, 256, 0, stream>>>(
            hin, (const bf16*)nullptr, Ut1, embW, x, cst, hout, h1seq, t);
        bf16* tmp = hin; hin = hout; hout = tmp;
    }

    // ---- layer 2 (K = 1024 (h1 via W2) + 512 (recurrent U2)) ----
    hipMemsetAsync(hin, 0, (size_t)2048 * 512 * sizeof(bf16), stream);
    hipMemsetAsync(cst, 0, (size_t)2048 * 512 * sizeof(float), stream);
    for (int t = 0; t < 64; ++t) {
        k_step<1><<<256, 256, 0, stream>>>(
            h1seq, hin, BigBt, b2r, (const int*)nullptr, cst, hout,
            (bf16*)nullptr, t);
        bf16* tmp = hin; hin = hout; hout = tmp;
    }
    // hin now holds the final layer-2 hidden state [2048][512] (swizzled)

    // ---- dense + relu, then output projection ----
    k_step<2><<<64, 256, 0, stream>>>(
        hin, hin + (size_t)1024 * 512, Wdt, bd, (const int*)nullptr,
        (float*)nullptr, dbuf, (bf16*)nullptr, 0);
    k_out<<<1024, 256, 0, stream>>>(dbuf, Wo, bo, (float*)d_out);
}